// Round 4
// baseline (7761.898 us; speedup 1.0000x reference)
//
#include <hip/hip_runtime.h>
#include <math.h>

// f32 inputs/outputs (reference dtype). Internal: f64 accumulation, f32
// activation storage at each layer boundary (matches reference
// materialization points). Workspace = EXACTLY A(16,777,216 f32) +
// B(8,388,608 f32) = 96 MiB — nothing else (prior rounds spilled 160 KB past
// 96 MiB; prime suspect for the deterministic 304.5 mismatch).

constexpr int TOPK_N = 200;

// ---------------------------------------------------------------------------
// Naive fused conv3x3(SAME)+bias+relu+maxpool2x2, f64 accumulators.
// One thread per pooled output (b, co, py, px).
// ---------------------------------------------------------------------------
template <int CIN>
__launch_bounds__(256)
__global__ void conv_relu_pool_naive(const float* __restrict__ in,
                                     const float* __restrict__ wgt,
                                     const float* __restrict__ bias,
                                     float* __restrict__ out,
                                     int Hin, int Win, int Cout) {
    const int Hp = Hin >> 1, Wp = Win >> 1;
    const int idx = blockIdx.x * 256 + threadIdx.x;
    const int total = 8 * Cout * Hp * Wp;  // B = 8
    if (idx >= total) return;
    const int px = idx % Wp;
    int t = idx / Wp;
    const int py = t % Hp; t /= Hp;
    const int co = t % Cout;
    const int b  = t / Cout;

    double a0 = 0.0, a1 = 0.0, a2 = 0.0, a3 = 0.0;  // pre-pool 2x2
    const int y0 = 2 * py, x0 = 2 * px;

    for (int ci = 0; ci < CIN; ++ci) {
        const float* ip = in + (size_t)((b * CIN + ci) * Hin) * Win;
        const float* wp = wgt + (co * CIN + ci) * 9;
        double w[9];
#pragma unroll
        for (int k = 0; k < 9; ++k) w[k] = (double)wp[k];

        double v[4][4];
#pragma unroll
        for (int dy = 0; dy < 4; ++dy) {
            const int y = y0 - 1 + dy;
#pragma unroll
            for (int dx = 0; dx < 4; ++dx) {
                const int x = x0 - 1 + dx;
                v[dy][dx] = (y >= 0 && y < Hin && x >= 0 && x < Win)
                              ? (double)ip[y * Win + x] : 0.0;
            }
        }
#pragma unroll
        for (int ky = 0; ky < 3; ++ky)
#pragma unroll
            for (int kx = 0; kx < 3; ++kx) {
                const double wv = w[ky * 3 + kx];
                a0 = fma(v[ky][kx],         wv, a0);
                a1 = fma(v[ky][kx + 1],     wv, a1);
                a2 = fma(v[ky + 1][kx],     wv, a2);
                a3 = fma(v[ky + 1][kx + 1], wv, a3);
            }
    }
    // Round each pre-pool element to f32 (ref materializes relu(x+b) in f32,
    // then pools over f32 values).
    const double bd = (double)bias[co];
    const float e0 = fmaxf((float)(a0 + bd), 0.f);
    const float e1 = fmaxf((float)(a1 + bd), 0.f);
    const float e2 = fmaxf((float)(a2 + bd), 0.f);
    const float e3 = fmaxf((float)(a3 + bd), 0.f);
    out[((size_t)(b * Cout + co) * Hp + py) * Wp + px] =
        fmaxf(fmaxf(e0, e1), fmaxf(e2, e3));
}

// ---------------------------------------------------------------------------
// Fused head(1x1 conv 256->5) + decode + top-200 + greedy NMS + output.
// One block per batch image (8 blocks x 256 threads). All scratch in LDS —
// zero global workspace beyond x4.
// ---------------------------------------------------------------------------
__launch_bounds__(256)
__global__ void head_topk_nms_k(const float* __restrict__ x4,
                                const float* __restrict__ wh,
                                const float* __restrict__ bh,
                                float* __restrict__ out5,
                                float* __restrict__ keep_out) {
    const int b = blockIdx.x, tid = threadIdx.x;
    __shared__ float s_wh[5 * 256];                  // 5 KB
    __shared__ float sbox[1024][4];                  // 16 KB
    __shared__ float sscore[1024];                   // 4 KB
    __shared__ unsigned long long key[1024];         // 8 KB
    __shared__ float bx1[TOPK_N], by1[TOPK_N], bx2[TOPK_N], by2[TOPK_N];
    __shared__ float sv[TOPK_N], ar[TOPK_N];
    __shared__ int   kp[TOPK_N];

    for (int i = tid; i < 1280; i += 256) s_wh[i] = wh[i];
    __syncthreads();

    // ---- head conv (f64 acc) + decode (f64, rounded to f32 boxes/scores) ----
    for (int cell = tid; cell < 1024; cell += 256) {
        double a[5];
#pragma unroll
        for (int o = 0; o < 5; ++o) a[o] = (double)bh[o];
        const float* xp = x4 + b * 262144 + cell;
        for (int ci = 0; ci < 256; ++ci) {
            const double v = (double)xp[ci << 10];
            a[0] = fma(v, (double)s_wh[0 * 256 + ci], a[0]);
            a[1] = fma(v, (double)s_wh[1 * 256 + ci], a[1]);
            a[2] = fma(v, (double)s_wh[2 * 256 + ci], a[2]);
            a[3] = fma(v, (double)s_wh[3 * 256 + ci], a[3]);
            a[4] = fma(v, (double)s_wh[4 * 256 + ci], a[4]);
        }
        const int gy = cell >> 5, gx = cell & 31;
        const double obj = 1.0 / (1.0 + exp(-a[0]));
        const double txs = 1.0 / (1.0 + exp(-a[1]));
        const double tys = 1.0 / (1.0 + exp(-a[2]));
        const double bw  = exp(a[3]) * 16.0;
        const double bhh = exp(a[4]) * 16.0;
        const double cx  = gx * 16.0 + txs * 16.0;
        const double cy  = gy * 16.0 + tys * 16.0;
        sbox[cell][0] = (float)fmin(fmax(cx - bw * 0.5, 0.0), 511.0);
        sbox[cell][1] = (float)fmin(fmax(cy - bhh * 0.5, 0.0), 511.0);
        sbox[cell][2] = (float)fmin(fmax(cx + bw * 0.5, 0.0), 511.0);
        sbox[cell][3] = (float)fmin(fmax(cy + bhh * 0.5, 0.0), 511.0);
        sscore[cell]  = (float)obj;
    }
    __syncthreads();

    // ---- keys: (orderable masked score, 1023-idx) for lax.top_k semantics ----
    for (int i = tid; i < 1024; i += 256) {
        float s = sscore[i];
        float m = (s >= 0.01f) ? s : -1.0f;
        unsigned u = __float_as_uint(m);
        u = (u & 0x80000000u) ? ~u : (u | 0x80000000u);
        key[i] = ((unsigned long long)u << 32) | (unsigned)(1023 - i);
    }
    __syncthreads();

    // ---- bitonic sort, descending ----
    for (int k = 2; k <= 1024; k <<= 1) {
        for (int j = k >> 1; j > 0; j >>= 1) {
            for (int i = tid; i < 1024; i += 256) {
                int l = i ^ j;
                if (l > i) {
                    unsigned long long a = key[i], c = key[l];
                    bool desc = ((i & k) == 0);
                    bool sw = desc ? (a < c) : (a > c);
                    if (sw) { key[i] = c; key[l] = a; }
                }
            }
            __syncthreads();
        }
    }

    // ---- gather top-200 ----
    for (int i = tid; i < TOPK_N; i += 256) {
        unsigned long long kk = key[i];
        unsigned u = (unsigned)(kk >> 32);
        unsigned bits = (u & 0x80000000u) ? (u & 0x7FFFFFFFu) : ~u;
        float s = __uint_as_float(bits);
        int src = 1023 - (int)(kk & 0xFFFFFFFFu);
        bx1[i] = sbox[src][0]; by1[i] = sbox[src][1];
        bx2[i] = sbox[src][2]; by2[i] = sbox[src][3];
        sv[i] = s;
        ar[i] = (bx2[i] - bx1[i]) * (by2[i] - by1[i]);
        kp[i] = (s >= 0.01f) ? 1 : 0;
    }
    __syncthreads();

    // ---- greedy NMS (matches reference fori_loop body, f32 IoU math) ----
    for (int i = 0; i < TOPK_N; ++i) {
        if (kp[i]) {
            const float X1 = bx1[i], Y1 = by1[i], X2 = bx2[i], Y2 = by2[i], A = ar[i];
            for (int j = tid; j < TOPK_N; j += 256) {
                if (j > i && kp[j]) {
                    float xx1 = fmaxf(X1, bx1[j]);
                    float yy1 = fmaxf(Y1, by1[j]);
                    float xx2 = fminf(X2, bx2[j]);
                    float yy2 = fminf(Y2, by2[j]);
                    float inter = fmaxf(xx2 - xx1, 0.f) * fmaxf(yy2 - yy1, 0.f);
                    float uni = A + ar[j] - inter;
                    float iou = inter / fmaxf(uni, 1e-6f);
                    if (iou > 0.5f) kp[j] = 0;
                }
            }
        }
        __syncthreads();
    }

    for (int i = tid; i < TOPK_N; i += 256) {
        float kf = kp[i] ? 1.f : 0.f;
        float s  = sv[i];
        float sc = (s >= 0.01f) ? s : 0.f;
        float* op = out5 + (b * TOPK_N + i) * 5;
        op[0] = bx1[i] * kf;
        op[1] = by1[i] * kf;
        op[2] = bx2[i] * kf;
        op[3] = by2[i] * kf;
        op[4] = sc * kf;
        keep_out[b * TOPK_N + i] = kf;
    }
}

extern "C" void kernel_launch(void* const* d_in, const int* in_sizes, int n_in,
                              void* d_out, int out_size, void* d_ws, size_t ws_size,
                              hipStream_t stream) {
    const float* images = (const float*)d_in[0];
    const float* w1 = (const float*)d_in[1];
    const float* b1 = (const float*)d_in[2];
    const float* w2 = (const float*)d_in[3];
    const float* b2 = (const float*)d_in[4];
    const float* w3 = (const float*)d_in[5];
    const float* b3 = (const float*)d_in[6];
    const float* w4 = (const float*)d_in[7];
    const float* b4 = (const float*)d_in[8];
    const float* wh = (const float*)d_in[9];
    const float* bh = (const float*)d_in[10];
    float* out = (float*)d_out;

    // Workspace: EXACTLY 96 MiB.
    //   A: 16,777,216 f32 — x1 [8,32,256,256], later x3 [8,128,64,64]
    //   B:  8,388,608 f32 — x2 [8,64,128,128], later x4 [8,256,32,32]
    float* A    = (float*)d_ws;
    float* Bbuf = A + 16777216;

    // L1: 3->32, 512x512 -> 256x256
    conv_relu_pool_naive<3><<<65536, 256, 0, stream>>>(images, w1, b1, A, 512, 512, 32);
    // L2: 32->64, 256x256 -> 128x128
    conv_relu_pool_naive<32><<<32768, 256, 0, stream>>>(A, w2, b2, Bbuf, 256, 256, 64);
    // L3: 64->128, 128x128 -> 64x64 (overwrites dead x1)
    conv_relu_pool_naive<64><<<16384, 256, 0, stream>>>(Bbuf, w3, b3, A, 128, 128, 128);
    // L4: 128->256, 64x64 -> 32x32 (overwrites dead x2)
    conv_relu_pool_naive<128><<<8192, 256, 0, stream>>>(A, w4, b4, Bbuf, 64, 64, 256);
    // Head + decode + top-k + NMS + output, all fused, zero global scratch
    head_topk_nms_k<<<8, 256, 0, stream>>>(Bbuf, wh, bh, out, out + 8 * TOPK_N * 5);
}

// Round 5
// 2169.067 us; speedup vs baseline: 3.5784x; 3.5784x over previous
//
#include <hip/hip_runtime.h>
#include <math.h>

// f32 I/O, f64 accumulation everywhere (matches np-f64 ref bit-exactly at the
// f32 materialization points — round 4 absmax was 0.0). Workspace EXACTLY
// 96 MiB: A(16,777,216 f32) + B(8,388,608 f32). No global scratch beyond that.

constexpr int TOPK_N = 200;

// ---------------------------------------------------------------------------
// Tiled fused conv3x3(SAME)+bias+relu+maxpool2x2, f64 accumulators.
// Block = 256 threads = 16x16 pooled outputs (32x32 pre-pool), CO_BLK=8 output
// channels per block, input staged in LDS per CI_BLK-channel chunk.
// Indexing validated (bit-identical to naive conv in rounds 1-2).
// ---------------------------------------------------------------------------
template <int CIN, int CI_BLK>
__launch_bounds__(256)
__global__ void conv_relu_pool_tiled(const float* __restrict__ in,
                                     const float* __restrict__ wgt,
                                     const float* __restrict__ bias,
                                     float* __restrict__ out,
                                     int Hin, int Win, int Cout) {
    constexpr int CO_BLK = 8;
    const int Hp = Hin >> 1, Wp = Win >> 1;
    const int coChunks = Cout >> 3;
    const int b  = blockIdx.z / coChunks;
    const int cz = blockIdx.z % coChunks;
    const int tid = threadIdx.x;
    const int tx = tid & 15, ty = tid >> 4;
    const int px = (blockIdx.x << 4) + tx;
    const int py = (blockIdx.y << 4) + ty;
    const int iy0 = (blockIdx.y << 5) - 1;
    const int ix0 = (blockIdx.x << 5) - 1;

    __shared__ float  s_in[CI_BLK][34][34];          // f32 tile + halo
    __shared__ double s_w[CI_BLK * 9 * CO_BLK];      // weights pre-cvt to f64

    double acc[CO_BLK][4];
#pragma unroll
    for (int co = 0; co < CO_BLK; ++co)
#pragma unroll
        for (int p = 0; p < 4; ++p) acc[co][p] = 0.0;

    for (int c0 = 0; c0 < CIN; c0 += CI_BLK) {
        // stage input tile (zero-padded at image borders)
        for (int idx = tid; idx < CI_BLK * 34 * 34; idx += 256) {
            int ci = idx / (34 * 34);
            int r  = idx - ci * 34 * 34;
            int ly = r / 34, lx = r - ly * 34;
            int iy = iy0 + ly, ix = ix0 + lx;
            float v = 0.f;
            if ((unsigned)iy < (unsigned)Hin && (unsigned)ix < (unsigned)Win)
                v = in[((size_t)(b * CIN + c0 + ci) * Hin + iy) * Win + ix];
            s_in[ci][ly][lx] = v;
        }
        // stage weights, converted to f64: s_w[(ci*9+k)*8 + co]
        for (int idx = tid; idx < CI_BLK * 9 * CO_BLK; idx += 256) {
            int co   = idx & 7;
            int rest = idx >> 3;
            int k    = rest % 9;
            int ci   = rest / 9;
            s_w[idx] = (double)wgt[((cz * 8 + co) * CIN + c0 + ci) * 9 + k];
        }
        __syncthreads();

#pragma unroll 1
        for (int ci = 0; ci < CI_BLK; ++ci) {
            double win[4][4];
#pragma unroll
            for (int iy = 0; iy < 4; ++iy) {
                float2 r0 = *(const float2*)&s_in[ci][2 * ty + iy][2 * tx];
                float2 r1 = *(const float2*)&s_in[ci][2 * ty + iy][2 * tx + 2];
                win[iy][0] = (double)r0.x; win[iy][1] = (double)r0.y;
                win[iy][2] = (double)r1.x; win[iy][3] = (double)r1.y;
            }
#pragma unroll
            for (int k = 0; k < 9; ++k) {
                const int ky = k / 3, kx = k % 3;
                const double* wp = &s_w[(ci * 9 + k) * 8];
                const double w0 = wp[0], w1 = wp[1], w2 = wp[2], w3 = wp[3];
                const double w4 = wp[4], w5 = wp[5], w6 = wp[6], w7 = wp[7];
#pragma unroll
                for (int p = 0; p < 4; ++p) {
                    const double v = win[(p >> 1) + ky][(p & 1) + kx];
                    acc[0][p] = fma(v, w0, acc[0][p]);
                    acc[1][p] = fma(v, w1, acc[1][p]);
                    acc[2][p] = fma(v, w2, acc[2][p]);
                    acc[3][p] = fma(v, w3, acc[3][p]);
                    acc[4][p] = fma(v, w4, acc[4][p]);
                    acc[5][p] = fma(v, w5, acc[5][p]);
                    acc[6][p] = fma(v, w6, acc[6][p]);
                    acc[7][p] = fma(v, w7, acc[7][p]);
                }
            }
        }
        __syncthreads();
    }

#pragma unroll
    for (int co = 0; co < CO_BLK; ++co) {
        const double bd = (double)bias[cz * 8 + co];
        const float e0 = fmaxf((float)(acc[co][0] + bd), 0.f);
        const float e1 = fmaxf((float)(acc[co][1] + bd), 0.f);
        const float e2 = fmaxf((float)(acc[co][2] + bd), 0.f);
        const float e3 = fmaxf((float)(acc[co][3] + bd), 0.f);
        out[((size_t)(b * Cout + cz * 8 + co) * Hp + py) * Wp + px] =
            fmaxf(fmaxf(e0, e1), fmaxf(e2, e3));
    }
}

// ---------------------------------------------------------------------------
// Fused head(1x1 conv 256->5, f64) + decode(f64) + top-200 + greedy NMS.
// One block per batch image. All scratch in LDS. (Unchanged from green R4.)
// ---------------------------------------------------------------------------
__launch_bounds__(256)
__global__ void head_topk_nms_k(const float* __restrict__ x4,
                                const float* __restrict__ wh,
                                const float* __restrict__ bh,
                                float* __restrict__ out5,
                                float* __restrict__ keep_out) {
    const int b = blockIdx.x, tid = threadIdx.x;
    __shared__ float s_wh[5 * 256];
    __shared__ float sbox[1024][4];
    __shared__ float sscore[1024];
    __shared__ unsigned long long key[1024];
    __shared__ float bx1[TOPK_N], by1[TOPK_N], bx2[TOPK_N], by2[TOPK_N];
    __shared__ float sv[TOPK_N], ar[TOPK_N];
    __shared__ int   kp[TOPK_N];

    for (int i = tid; i < 1280; i += 256) s_wh[i] = wh[i];
    __syncthreads();

    for (int cell = tid; cell < 1024; cell += 256) {
        double a[5];
#pragma unroll
        for (int o = 0; o < 5; ++o) a[o] = (double)bh[o];
        const float* xp = x4 + b * 262144 + cell;
        for (int ci = 0; ci < 256; ++ci) {
            const double v = (double)xp[ci << 10];
            a[0] = fma(v, (double)s_wh[0 * 256 + ci], a[0]);
            a[1] = fma(v, (double)s_wh[1 * 256 + ci], a[1]);
            a[2] = fma(v, (double)s_wh[2 * 256 + ci], a[2]);
            a[3] = fma(v, (double)s_wh[3 * 256 + ci], a[3]);
            a[4] = fma(v, (double)s_wh[4 * 256 + ci], a[4]);
        }
        const int gy = cell >> 5, gx = cell & 31;
        const double obj = 1.0 / (1.0 + exp(-a[0]));
        const double txs = 1.0 / (1.0 + exp(-a[1]));
        const double tys = 1.0 / (1.0 + exp(-a[2]));
        const double bw  = exp(a[3]) * 16.0;
        const double bhh = exp(a[4]) * 16.0;
        const double cx  = gx * 16.0 + txs * 16.0;
        const double cy  = gy * 16.0 + tys * 16.0;
        sbox[cell][0] = (float)fmin(fmax(cx - bw * 0.5, 0.0), 511.0);
        sbox[cell][1] = (float)fmin(fmax(cy - bhh * 0.5, 0.0), 511.0);
        sbox[cell][2] = (float)fmin(fmax(cx + bw * 0.5, 0.0), 511.0);
        sbox[cell][3] = (float)fmin(fmax(cy + bhh * 0.5, 0.0), 511.0);
        sscore[cell]  = (float)obj;
    }
    __syncthreads();

    for (int i = tid; i < 1024; i += 256) {
        float s = sscore[i];
        float m = (s >= 0.01f) ? s : -1.0f;
        unsigned u = __float_as_uint(m);
        u = (u & 0x80000000u) ? ~u : (u | 0x80000000u);
        key[i] = ((unsigned long long)u << 32) | (unsigned)(1023 - i);
    }
    __syncthreads();

    for (int k = 2; k <= 1024; k <<= 1) {
        for (int j = k >> 1; j > 0; j >>= 1) {
            for (int i = tid; i < 1024; i += 256) {
                int l = i ^ j;
                if (l > i) {
                    unsigned long long a = key[i], c = key[l];
                    bool desc = ((i & k) == 0);
                    bool sw = desc ? (a < c) : (a > c);
                    if (sw) { key[i] = c; key[l] = a; }
                }
            }
            __syncthreads();
        }
    }

    for (int i = tid; i < TOPK_N; i += 256) {
        unsigned long long kk = key[i];
        unsigned u = (unsigned)(kk >> 32);
        unsigned bits = (u & 0x80000000u) ? (u & 0x7FFFFFFFu) : ~u;
        float s = __uint_as_float(bits);
        int src = 1023 - (int)(kk & 0xFFFFFFFFu);
        bx1[i] = sbox[src][0]; by1[i] = sbox[src][1];
        bx2[i] = sbox[src][2]; by2[i] = sbox[src][3];
        sv[i] = s;
        ar[i] = (bx2[i] - bx1[i]) * (by2[i] - by1[i]);
        kp[i] = (s >= 0.01f) ? 1 : 0;
    }
    __syncthreads();

    for (int i = 0; i < TOPK_N; ++i) {
        if (kp[i]) {
            const float X1 = bx1[i], Y1 = by1[i], X2 = bx2[i], Y2 = by2[i], A = ar[i];
            for (int j = tid; j < TOPK_N; j += 256) {
                if (j > i && kp[j]) {
                    float xx1 = fmaxf(X1, bx1[j]);
                    float yy1 = fmaxf(Y1, by1[j]);
                    float xx2 = fminf(X2, bx2[j]);
                    float yy2 = fminf(Y2, by2[j]);
                    float inter = fmaxf(xx2 - xx1, 0.f) * fmaxf(yy2 - yy1, 0.f);
                    float uni = A + ar[j] - inter;
                    float iou = inter / fmaxf(uni, 1e-6f);
                    if (iou > 0.5f) kp[j] = 0;
                }
            }
        }
        __syncthreads();
    }

    for (int i = tid; i < TOPK_N; i += 256) {
        float kf = kp[i] ? 1.f : 0.f;
        float s  = sv[i];
        float sc = (s >= 0.01f) ? s : 0.f;
        float* op = out5 + (b * TOPK_N + i) * 5;
        op[0] = bx1[i] * kf;
        op[1] = by1[i] * kf;
        op[2] = bx2[i] * kf;
        op[3] = by2[i] * kf;
        op[4] = sc * kf;
        keep_out[b * TOPK_N + i] = kf;
    }
}

extern "C" void kernel_launch(void* const* d_in, const int* in_sizes, int n_in,
                              void* d_out, int out_size, void* d_ws, size_t ws_size,
                              hipStream_t stream) {
    const float* images = (const float*)d_in[0];
    const float* w1 = (const float*)d_in[1];
    const float* b1 = (const float*)d_in[2];
    const float* w2 = (const float*)d_in[3];
    const float* b2 = (const float*)d_in[4];
    const float* w3 = (const float*)d_in[5];
    const float* b3 = (const float*)d_in[6];
    const float* w4 = (const float*)d_in[7];
    const float* b4 = (const float*)d_in[8];
    const float* wh = (const float*)d_in[9];
    const float* bh = (const float*)d_in[10];
    float* out = (float*)d_out;

    float* A    = (float*)d_ws;          // x1 [8,32,256,256] -> x3 [8,128,64,64]
    float* Bbuf = A + 16777216;          // x2 [8,64,128,128] -> x4 [8,256,32,32]

    // L1: 3->32, 512x512 -> 256x256 pooled
    conv_relu_pool_tiled<3, 3><<<dim3(16, 16, 8 * 4), 256, 0, stream>>>(
        images, w1, b1, A, 512, 512, 32);
    // L2: 32->64, 256x256 -> 128x128
    conv_relu_pool_tiled<32, 8><<<dim3(8, 8, 8 * 8), 256, 0, stream>>>(
        A, w2, b2, Bbuf, 256, 256, 64);
    // L3: 64->128, 128x128 -> 64x64
    conv_relu_pool_tiled<64, 8><<<dim3(4, 4, 8 * 16), 256, 0, stream>>>(
        Bbuf, w3, b3, A, 128, 128, 128);
    // L4: 128->256, 64x64 -> 32x32
    conv_relu_pool_tiled<128, 8><<<dim3(2, 2, 8 * 32), 256, 0, stream>>>(
        A, w4, b4, Bbuf, 64, 64, 256);
    // Head + decode + top-k + NMS + output
    head_topk_nms_k<<<8, 256, 0, stream>>>(Bbuf, wh, bh, out, out + 8 * TOPK_N * 5);
}

// Round 6
// 1943.757 us; speedup vs baseline: 3.9932x; 1.1159x over previous
//
#include <hip/hip_runtime.h>
#include <math.h>

// f32 I/O, f64 accumulation everywhere (bit-exact vs np ref at f32
// materialization points — absmax 0.0 in R4/R5; f64 acc is order-insensitive
// after f32 rounding). Workspace EXACTLY 96 MiB: A(16,777,216 f32) +
// B(8,388,608 f32).

constexpr int TOPK_N = 200;

// ---------------------------------------------------------------------------
// Tiled fused conv3x3(SAME)+bias+relu+maxpool2x2, f64 accumulators.
// Block = 256 threads = 16x16 pooled outputs (32x32 pre-pool), CO_BLK output
// channels per block, input staged in LDS per CI_BLK-channel chunk.
// R6: CI_BLK=4 (LDS ~21 KB -> ~7 blocks/CU) + per-layer CO_BLK for grid size.
// ---------------------------------------------------------------------------
template <int CIN, int CI_BLK, int CO_BLK>
__launch_bounds__(256)
__global__ void conv_relu_pool_tiled(const float* __restrict__ in,
                                     const float* __restrict__ wgt,
                                     const float* __restrict__ bias,
                                     float* __restrict__ out,
                                     int Hin, int Win, int Cout) {
    const int Hp = Hin >> 1, Wp = Win >> 1;
    const int coChunks = Cout / CO_BLK;
    const int b  = blockIdx.z / coChunks;
    const int cz = blockIdx.z % coChunks;
    const int tid = threadIdx.x;
    const int tx = tid & 15, ty = tid >> 4;
    const int px = (blockIdx.x << 4) + tx;
    const int py = (blockIdx.y << 4) + ty;
    const int iy0 = (blockIdx.y << 5) - 1;
    const int ix0 = (blockIdx.x << 5) - 1;

    __shared__ float  s_in[CI_BLK][34][34];          // f32 tile + halo
    __shared__ double s_w[CI_BLK * 9 * CO_BLK];      // weights pre-cvt to f64

    double acc[CO_BLK][4];
#pragma unroll
    for (int co = 0; co < CO_BLK; ++co)
#pragma unroll
        for (int p = 0; p < 4; ++p) acc[co][p] = 0.0;

    for (int c0 = 0; c0 < CIN; c0 += CI_BLK) {
        // stage input tile (zero-padded at image borders)
        for (int idx = tid; idx < CI_BLK * 34 * 34; idx += 256) {
            int ci = idx / (34 * 34);
            int r  = idx - ci * 34 * 34;
            int ly = r / 34, lx = r - ly * 34;
            int iy = iy0 + ly, ix = ix0 + lx;
            float v = 0.f;
            if ((unsigned)iy < (unsigned)Hin && (unsigned)ix < (unsigned)Win)
                v = in[((size_t)(b * CIN + c0 + ci) * Hin + iy) * Win + ix];
            s_in[ci][ly][lx] = v;
        }
        // stage weights, converted to f64: s_w[(ci*9+k)*CO_BLK + co]
        for (int idx = tid; idx < CI_BLK * 9 * CO_BLK; idx += 256) {
            int co   = idx & (CO_BLK - 1);
            int rest = idx / CO_BLK;
            int k    = rest % 9;
            int ci   = rest / 9;
            s_w[idx] = (double)wgt[((cz * CO_BLK + co) * CIN + c0 + ci) * 9 + k];
        }
        __syncthreads();

#pragma unroll 1
        for (int ci = 0; ci < CI_BLK; ++ci) {
            double win[4][4];
#pragma unroll
            for (int iy = 0; iy < 4; ++iy) {
                float2 r0 = *(const float2*)&s_in[ci][2 * ty + iy][2 * tx];
                float2 r1 = *(const float2*)&s_in[ci][2 * ty + iy][2 * tx + 2];
                win[iy][0] = (double)r0.x; win[iy][1] = (double)r0.y;
                win[iy][2] = (double)r1.x; win[iy][3] = (double)r1.y;
            }
#pragma unroll
            for (int k = 0; k < 9; ++k) {
                const int ky = k / 3, kx = k % 3;
                const double* wp = &s_w[(ci * 9 + k) * CO_BLK];
                double w[CO_BLK];
#pragma unroll
                for (int co = 0; co < CO_BLK; ++co) w[co] = wp[co];
#pragma unroll
                for (int p = 0; p < 4; ++p) {
                    const double v = win[(p >> 1) + ky][(p & 1) + kx];
#pragma unroll
                    for (int co = 0; co < CO_BLK; ++co)
                        acc[co][p] = fma(v, w[co], acc[co][p]);
                }
            }
        }
        __syncthreads();
    }

#pragma unroll
    for (int co = 0; co < CO_BLK; ++co) {
        const double bd = (double)bias[cz * CO_BLK + co];
        const float e0 = fmaxf((float)(acc[co][0] + bd), 0.f);
        const float e1 = fmaxf((float)(acc[co][1] + bd), 0.f);
        const float e2 = fmaxf((float)(acc[co][2] + bd), 0.f);
        const float e3 = fmaxf((float)(acc[co][3] + bd), 0.f);
        out[((size_t)(b * Cout + cz * CO_BLK + co) * Hp + py) * Wp + px] =
            fmaxf(fmaxf(e0, e1), fmaxf(e2, e3));
    }
}

// ---------------------------------------------------------------------------
// Fused head(1x1 conv 256->5, f64) + decode(f64) + top-200 + greedy NMS.
// One block per batch image. All scratch in LDS. (Unchanged — green since R4.)
// ---------------------------------------------------------------------------
__launch_bounds__(256)
__global__ void head_topk_nms_k(const float* __restrict__ x4,
                                const float* __restrict__ wh,
                                const float* __restrict__ bh,
                                float* __restrict__ out5,
                                float* __restrict__ keep_out) {
    const int b = blockIdx.x, tid = threadIdx.x;
    __shared__ float s_wh[5 * 256];
    __shared__ float sbox[1024][4];
    __shared__ float sscore[1024];
    __shared__ unsigned long long key[1024];
    __shared__ float bx1[TOPK_N], by1[TOPK_N], bx2[TOPK_N], by2[TOPK_N];
    __shared__ float sv[TOPK_N], ar[TOPK_N];
    __shared__ int   kp[TOPK_N];

    for (int i = tid; i < 1280; i += 256) s_wh[i] = wh[i];
    __syncthreads();

    for (int cell = tid; cell < 1024; cell += 256) {
        double a[5];
#pragma unroll
        for (int o = 0; o < 5; ++o) a[o] = (double)bh[o];
        const float* xp = x4 + b * 262144 + cell;
        for (int ci = 0; ci < 256; ++ci) {
            const double v = (double)xp[ci << 10];
            a[0] = fma(v, (double)s_wh[0 * 256 + ci], a[0]);
            a[1] = fma(v, (double)s_wh[1 * 256 + ci], a[1]);
            a[2] = fma(v, (double)s_wh[2 * 256 + ci], a[2]);
            a[3] = fma(v, (double)s_wh[3 * 256 + ci], a[3]);
            a[4] = fma(v, (double)s_wh[4 * 256 + ci], a[4]);
        }
        const int gy = cell >> 5, gx = cell & 31;
        const double obj = 1.0 / (1.0 + exp(-a[0]));
        const double txs = 1.0 / (1.0 + exp(-a[1]));
        const double tys = 1.0 / (1.0 + exp(-a[2]));
        const double bw  = exp(a[3]) * 16.0;
        const double bhh = exp(a[4]) * 16.0;
        const double cx  = gx * 16.0 + txs * 16.0;
        const double cy  = gy * 16.0 + tys * 16.0;
        sbox[cell][0] = (float)fmin(fmax(cx - bw * 0.5, 0.0), 511.0);
        sbox[cell][1] = (float)fmin(fmax(cy - bhh * 0.5, 0.0), 511.0);
        sbox[cell][2] = (float)fmin(fmax(cx + bw * 0.5, 0.0), 511.0);
        sbox[cell][3] = (float)fmin(fmax(cy + bhh * 0.5, 0.0), 511.0);
        sscore[cell]  = (float)obj;
    }
    __syncthreads();

    for (int i = tid; i < 1024; i += 256) {
        float s = sscore[i];
        float m = (s >= 0.01f) ? s : -1.0f;
        unsigned u = __float_as_uint(m);
        u = (u & 0x80000000u) ? ~u : (u | 0x80000000u);
        key[i] = ((unsigned long long)u << 32) | (unsigned)(1023 - i);
    }
    __syncthreads();

    for (int k = 2; k <= 1024; k <<= 1) {
        for (int j = k >> 1; j > 0; j >>= 1) {
            for (int i = tid; i < 1024; i += 256) {
                int l = i ^ j;
                if (l > i) {
                    unsigned long long a = key[i], c = key[l];
                    bool desc = ((i & k) == 0);
                    bool sw = desc ? (a < c) : (a > c);
                    if (sw) { key[i] = c; key[l] = a; }
                }
            }
            __syncthreads();
        }
    }

    for (int i = tid; i < TOPK_N; i += 256) {
        unsigned long long kk = key[i];
        unsigned u = (unsigned)(kk >> 32);
        unsigned bits = (u & 0x80000000u) ? (u & 0x7FFFFFFFu) : ~u;
        float s = __uint_as_float(bits);
        int src = 1023 - (int)(kk & 0xFFFFFFFFu);
        bx1[i] = sbox[src][0]; by1[i] = sbox[src][1];
        bx2[i] = sbox[src][2]; by2[i] = sbox[src][3];
        sv[i] = s;
        ar[i] = (bx2[i] - bx1[i]) * (by2[i] - by1[i]);
        kp[i] = (s >= 0.01f) ? 1 : 0;
    }
    __syncthreads();

    for (int i = 0; i < TOPK_N; ++i) {
        if (kp[i]) {
            const float X1 = bx1[i], Y1 = by1[i], X2 = bx2[i], Y2 = by2[i], A = ar[i];
            for (int j = tid; j < TOPK_N; j += 256) {
                if (j > i && kp[j]) {
                    float xx1 = fmaxf(X1, bx1[j]);
                    float yy1 = fmaxf(Y1, by1[j]);
                    float xx2 = fminf(X2, bx2[j]);
                    float yy2 = fminf(Y2, by2[j]);
                    float inter = fmaxf(xx2 - xx1, 0.f) * fmaxf(yy2 - yy1, 0.f);
                    float uni = A + ar[j] - inter;
                    float iou = inter / fmaxf(uni, 1e-6f);
                    if (iou > 0.5f) kp[j] = 0;
                }
            }
        }
        __syncthreads();
    }

    for (int i = tid; i < TOPK_N; i += 256) {
        float kf = kp[i] ? 1.f : 0.f;
        float s  = sv[i];
        float sc = (s >= 0.01f) ? s : 0.f;
        float* op = out5 + (b * TOPK_N + i) * 5;
        op[0] = bx1[i] * kf;
        op[1] = by1[i] * kf;
        op[2] = bx2[i] * kf;
        op[3] = by2[i] * kf;
        op[4] = sc * kf;
        keep_out[b * TOPK_N + i] = kf;
    }
}

extern "C" void kernel_launch(void* const* d_in, const int* in_sizes, int n_in,
                              void* d_out, int out_size, void* d_ws, size_t ws_size,
                              hipStream_t stream) {
    const float* images = (const float*)d_in[0];
    const float* w1 = (const float*)d_in[1];
    const float* b1 = (const float*)d_in[2];
    const float* w2 = (const float*)d_in[3];
    const float* b2 = (const float*)d_in[4];
    const float* w3 = (const float*)d_in[5];
    const float* b3 = (const float*)d_in[6];
    const float* w4 = (const float*)d_in[7];
    const float* b4 = (const float*)d_in[8];
    const float* wh = (const float*)d_in[9];
    const float* bh = (const float*)d_in[10];
    float* out = (float*)d_out;

    float* A    = (float*)d_ws;          // x1 [8,32,256,256] -> x3 [8,128,64,64]
    float* Bbuf = A + 16777216;          // x2 [8,64,128,128] -> x4 [8,256,32,32]

    // L1: 3->32, 512x512 -> 256x256 pooled. LDS ~15.6 KB, 8192 blocks.
    conv_relu_pool_tiled<3, 3, 8><<<dim3(16, 16, 8 * 4), 256, 0, stream>>>(
        images, w1, b1, A, 512, 512, 32);
    // L2: 32->64, 256x256 -> 128x128. CI_BLK=4 -> ~21 KB LDS, 4096 blocks.
    conv_relu_pool_tiled<32, 4, 8><<<dim3(8, 8, 8 * 8), 256, 0, stream>>>(
        A, w2, b2, Bbuf, 256, 256, 64);
    // L3: 64->128, 128x128 -> 64x64. 2048 blocks.
    conv_relu_pool_tiled<64, 4, 8><<<dim3(4, 4, 8 * 16), 256, 0, stream>>>(
        Bbuf, w3, b3, A, 128, 128, 128);
    // L4: 128->256, 64x64 -> 32x32. CO_BLK=4 -> 2048 blocks for residency.
    conv_relu_pool_tiled<128, 4, 4><<<dim3(2, 2, 8 * 64), 256, 0, stream>>>(
        A, w4, b4, Bbuf, 64, 64, 256);
    // Head + decode + top-k + NMS + output
    head_topk_nms_k<<<8, 256, 0, stream>>>(Bbuf, wh, bh, out, out + 8 * TOPK_N * 5);
}